// Round 3
// baseline (515.848 us; speedup 1.0000x reference)
//
#include <hip/hip_runtime.h>
#include <cstdint>
#include <cstddef>

#define D_IN  512
#define D_H   128
#define D_OUT 64

typedef __attribute__((ext_vector_type(8))) short bf16x8;
typedef __attribute__((ext_vector_type(4))) float f32x4;

__device__ __forceinline__ float bf2f(unsigned short u) {
  union { unsigned int i; float f; } v; v.i = ((unsigned int)u) << 16; return v.f;
}
__device__ __forceinline__ unsigned short f2bf(float f) {
  union { unsigned int i; float f; } v; v.f = f;
  unsigned int r = v.i + 0x7FFFu + ((v.i >> 16) & 1u);
  return (unsigned short)(r >> 16);
}

// ---------------- workspace layout (bytes), ws floor ~26.2 MB ----------------
#define OFF_RP    0u          // row_ptr int32[100001]
#define OFF_W0T   400384u     // W0^T bf16 128x512                (131072)
#define OFF_W1TP  531456u     // W1'^T bf16 64x128                (16384)
#define OFF_SACC  547840u     // stats accum fp32[256] (sum|sq)
#define OFF_MEAN  548864u     // fp32[128]
#define OFF_ISTD  549376u     // fp32[128]
#define OFF_CVEC  549888u     // fp32[64]
#define OFF_H     550912u     // h bf16 100000x128                (25600000)
#define END_H     26150912u
#define END_HW    38950912u   // END_H + hw bf16 100000x64 (12.8MB)

__global__ void k_zero(float* __restrict__ sacc) { sacc[threadIdx.x] = 0.f; }

// ---------------- row_ptr via binary search (row is sorted) ----------------
__global__ void k_rowptr(const int* __restrict__ row, int* __restrict__ rp,
                         int n, int e) {
  int i = blockIdx.x * blockDim.x + threadIdx.x;
  if (i > n) return;
  int lo = 0, hi = e;
  while (lo < hi) { int mid = (lo + hi) >> 1; if (row[mid] < i) lo = mid + 1; else hi = mid; }
  rp[i] = lo;
}

// -------- W0 transpose+convert: W0t[n][k] = bf16(W0[k][n]), W0 fp32 ---------
__global__ void k_transpose_w0(const float* __restrict__ W0,
                               unsigned short* __restrict__ W0t) {
  int idx = blockIdx.x * blockDim.x + threadIdx.x;  // 65536
  int k = idx & (D_IN - 1);
  int n = idx >> 9;
  W0t[n * D_IN + k] = f2bf(W0[k * D_H + n]);
}

// ---- GEMM1: xw(bf16) = x(fp32) @ W0 : tile 128x128, BK=32, 4 waves (2x2) ----
// LDS fragment-chunk order [k8][m][8]: every MFMA operand read = ds_read_b128.
// A is fp32: convert to bf16 during staging.
__global__ __launch_bounds__(256) void k_gemm1(const float* __restrict__ A,
                                               const unsigned short* __restrict__ Bt,
                                               unsigned short* __restrict__ C,
                                               int M) {
  __shared__ unsigned short Ash[4 * 128 * 8];  // 8KB
  __shared__ unsigned short Bsh[4 * 128 * 8];  // 8KB
  const int tid  = threadIdx.x;
  const int lane = tid & 63;
  const int wave = tid >> 6;
  const int wm = (wave >> 1) * 64;
  const int wn = (wave & 1) * 64;
  const int m0 = blockIdx.x * 128;
  const int quad = lane >> 4;
  const int l16  = lane & 15;
  f32x4 acc[4][4] = {};

  for (int k0 = 0; k0 < D_IN; k0 += 32) {
    __syncthreads();
#pragma unroll
    for (int i = 0; i < 2; ++i) {
      int c = tid + i * 256;          // 512 chunks each for A and B
      int m = c >> 2, k8 = c & 3;
      int gm = m0 + m; if (gm >= M) gm = M - 1;
      const float* src = &A[(size_t)gm * D_IN + k0 + k8 * 8];
      f32x4 f0 = *(const f32x4*)src;
      f32x4 f1 = *(const f32x4*)(src + 4);
      bf16x8 pk;
#pragma unroll
      for (int j = 0; j < 4; ++j) { pk[j] = (short)f2bf(f0[j]); pk[4 + j] = (short)f2bf(f1[j]); }
      *(bf16x8*)&Ash[(k8 * 128 + m) * 8] = pk;
      *(bf16x8*)&Bsh[(k8 * 128 + m) * 8] =
          *(const bf16x8*)&Bt[(size_t)m * D_IN + k0 + k8 * 8];
    }
    __syncthreads();
    bf16x8 af[4], bfv[4];
#pragma unroll
    for (int mf = 0; mf < 4; ++mf)
      af[mf] = *(const bf16x8*)&Ash[(quad * 128 + (wm + mf * 16 + l16)) * 8];
#pragma unroll
    for (int nf = 0; nf < 4; ++nf)
      bfv[nf] = *(const bf16x8*)&Bsh[(quad * 128 + (wn + nf * 16 + l16)) * 8];
#pragma unroll
    for (int mf = 0; mf < 4; ++mf)
#pragma unroll
      for (int nf = 0; nf < 4; ++nf)
        acc[mf][nf] = __builtin_amdgcn_mfma_f32_16x16x32_bf16(af[mf], bfv[nf], acc[mf][nf], 0, 0, 0);
  }
  // C/D layout: row = quad*4 + i, col = lane&15  [m89/m91-verified]
#pragma unroll
  for (int mf = 0; mf < 4; ++mf)
#pragma unroll
    for (int nf = 0; nf < 4; ++nf)
#pragma unroll
      for (int i = 0; i < 4; ++i) {
        int r = m0 + wm + mf * 16 + quad * 4 + i;
        int cc = wn + nf * 16 + l16;
        if (r < M) C[(size_t)r * D_H + cc] = f2bf(acc[mf][nf][i]);
      }
}

// ---- SpMM1: h = relu(adj @ xw + b0); one wave/node, lane = packed feat pair
__global__ __launch_bounds__(256) void k_spmm1(const unsigned int* __restrict__ xw2,
                                               const float* __restrict__ adj,
                                               const int* __restrict__ col,
                                               const int* __restrict__ rp,
                                               const float* __restrict__ b0,
                                               unsigned int* __restrict__ h2,
                                               int n) {
  int node = blockIdx.x * 4 + (threadIdx.x >> 6);
  if (node >= n) return;
  int l = threadIdx.x & 63;
  int e0 = rp[node], e1 = rp[node + 1];
  float a0 = 0.f, a1 = 0.f;
  int e = e0;
  for (; e + 4 <= e1; e += 4) {
    int c0 = col[e], c1 = col[e + 1], c2 = col[e + 2], c3 = col[e + 3];
    float v0 = adj[e], v1 = adj[e + 1], v2 = adj[e + 2], v3 = adj[e + 3];
    unsigned int p0 = xw2[(size_t)c0 * 64 + l];
    unsigned int p1 = xw2[(size_t)c1 * 64 + l];
    unsigned int p2 = xw2[(size_t)c2 * 64 + l];
    unsigned int p3 = xw2[(size_t)c3 * 64 + l];
    a0 += v0 * bf2f((unsigned short)(p0 & 0xFFFF)); a1 += v0 * bf2f((unsigned short)(p0 >> 16));
    a0 += v1 * bf2f((unsigned short)(p1 & 0xFFFF)); a1 += v1 * bf2f((unsigned short)(p1 >> 16));
    a0 += v2 * bf2f((unsigned short)(p2 & 0xFFFF)); a1 += v2 * bf2f((unsigned short)(p2 >> 16));
    a0 += v3 * bf2f((unsigned short)(p3 & 0xFFFF)); a1 += v3 * bf2f((unsigned short)(p3 >> 16));
  }
  for (; e < e1; ++e) {
    int c = col[e];
    float v = adj[e];
    unsigned int p = xw2[(size_t)c * 64 + l];
    a0 += v * bf2f((unsigned short)(p & 0xFFFF));
    a1 += v * bf2f((unsigned short)(p >> 16));
  }
  float r0 = fmaxf(a0 + b0[2 * l], 0.f);
  float r1 = fmaxf(a1 + b0[2 * l + 1], 0.f);
  h2[(size_t)node * 64 + l] = ((unsigned int)f2bf(r1) << 16) | (unsigned int)f2bf(r0);
}

// ---------------- BN stats: atomic accumulation of sum / sumsq ----------------
__global__ __launch_bounds__(256) void k_stats(const unsigned short* __restrict__ h,
                                               float* __restrict__ sacc, int n) {
  __shared__ float ss[256], sq[256];
  int t = threadIdx.x;
  int f = t & 127, half = t >> 7;
  float s = 0.f, q = 0.f;
  for (int r = blockIdx.x * 2 + half; r < n; r += gridDim.x * 2) {
    float v = bf2f(h[(size_t)r * D_H + f]);
    s += v; q += v * v;
  }
  ss[t] = s; sq[t] = q;
  __syncthreads();
  if (t < 128) {
    atomicAdd(&sacc[f],       ss[t] + ss[t + 128]);
    atomicAdd(&sacc[128 + f], sq[t] + sq[t + 128]);
  }
}

__global__ void k_redstats(const float* __restrict__ sacc,
                           float* __restrict__ mean, float* __restrict__ istd, int n) {
  int f = threadIdx.x;  // 128
  float m = sacc[f] / (float)n;
  float var = sacc[128 + f] / (float)n - m * m;
  if (var < 0.f) var = 0.f;
  mean[f] = m;
  istd[f] = rsqrtf(var + 1e-5f);
}

// -- fold BN into layer 2: W1'[k][n]=istd[k]*W1[k][n]; c=-(mean*istd)@W1 (fp32 W1)
__global__ void k_prep(const float* __restrict__ W1,
                       const float* __restrict__ mean, const float* __restrict__ istd,
                       unsigned short* __restrict__ W1tp, float* __restrict__ cvec) {
  int t = threadIdx.x;  // 256
  for (int idx = t; idx < D_OUT * D_H; idx += 256) {
    int nn = idx >> 7, k = idx & 127;
    W1tp[nn * D_H + k] = f2bf(istd[k] * W1[k * D_OUT + nn]);
  }
  if (t < D_OUT) {
    float a = 0.f;
    for (int k = 0; k < D_H; ++k) a += mean[k] * istd[k] * W1[k * D_OUT + t];
    cvec[t] = -a;
  }
}

// ---- GEMM2: hw(bf16) = h(bf16) @ W1' + c : tile 128x64, BK=32, 4 waves ------
__global__ __launch_bounds__(256) void k_gemm2(const unsigned short* __restrict__ A,
                                               const unsigned short* __restrict__ Bt,
                                               const float* __restrict__ cvec,
                                               unsigned short* __restrict__ Cout,
                                               int M) {
  __shared__ unsigned short Ash[4 * 128 * 8];  // 8KB
  __shared__ unsigned short Bsh[4 * 64 * 8];   // 4KB
  const int tid  = threadIdx.x;
  const int lane = tid & 63;
  const int wave = tid >> 6;
  const int wm = wave * 32;
  const int m0 = blockIdx.x * 128;
  const int quad = lane >> 4;
  const int l16  = lane & 15;
  f32x4 acc[2][4] = {};

  for (int k0 = 0; k0 < D_H; k0 += 32) {
    __syncthreads();
#pragma unroll
    for (int i = 0; i < 2; ++i) {
      int c = tid + i * 256;          // 512 A-chunks
      int m = c >> 2, k8 = c & 3;
      int gm = m0 + m; if (gm >= M) gm = M - 1;
      *(bf16x8*)&Ash[(k8 * 128 + m) * 8] =
          *(const bf16x8*)&A[(size_t)gm * D_H + k0 + k8 * 8];
    }
    {
      int nn = tid >> 2, k8 = tid & 3;  // 256 B-chunks
      *(bf16x8*)&Bsh[(k8 * 64 + nn) * 8] =
          *(const bf16x8*)&Bt[(size_t)nn * D_H + k0 + k8 * 8];
    }
    __syncthreads();
    bf16x8 af[2], bfv[4];
#pragma unroll
    for (int mf = 0; mf < 2; ++mf)
      af[mf] = *(const bf16x8*)&Ash[(quad * 128 + (wm + mf * 16 + l16)) * 8];
#pragma unroll
    for (int nf = 0; nf < 4; ++nf)
      bfv[nf] = *(const bf16x8*)&Bsh[(quad * 64 + (nf * 16 + l16)) * 8];
#pragma unroll
    for (int mf = 0; mf < 2; ++mf)
#pragma unroll
      for (int nf = 0; nf < 4; ++nf)
        acc[mf][nf] = __builtin_amdgcn_mfma_f32_16x16x32_bf16(af[mf], bfv[nf], acc[mf][nf], 0, 0, 0);
  }
#pragma unroll
  for (int mf = 0; mf < 2; ++mf)
#pragma unroll
    for (int nf = 0; nf < 4; ++nf)
#pragma unroll
      for (int i = 0; i < 4; ++i) {
        int r = m0 + wm + mf * 16 + quad * 4 + i;
        int cc = nf * 16 + l16;
        if (r < M) Cout[(size_t)r * 64 + cc] = f2bf(acc[mf][nf][i] + cvec[cc]);
      }
}

// ---- SpMM2: out(fp32) = adj @ hw + b1; one wave/node, lane = packed pair ----
__global__ __launch_bounds__(256) void k_spmm2(const unsigned int* __restrict__ hw2,
                                               const float* __restrict__ adj,
                                               const int* __restrict__ col,
                                               const int* __restrict__ rp,
                                               const float* __restrict__ b1,
                                               float2* __restrict__ o2,
                                               int n) {
  int node = blockIdx.x * 8 + (threadIdx.x >> 5);
  if (node >= n) return;
  int l = threadIdx.x & 31;
  int e0 = rp[node], e1 = rp[node + 1];
  float a0 = 0.f, a1 = 0.f;
  int e = e0;
  for (; e + 4 <= e1; e += 4) {
    int c0 = col[e], c1 = col[e + 1], c2 = col[e + 2], c3 = col[e + 3];
    float v0 = adj[e], v1 = adj[e + 1], v2 = adj[e + 2], v3 = adj[e + 3];
    unsigned int p0 = hw2[(size_t)c0 * 32 + l];
    unsigned int p1 = hw2[(size_t)c1 * 32 + l];
    unsigned int p2 = hw2[(size_t)c2 * 32 + l];
    unsigned int p3 = hw2[(size_t)c3 * 32 + l];
    a0 += v0 * bf2f((unsigned short)(p0 & 0xFFFF)); a1 += v0 * bf2f((unsigned short)(p0 >> 16));
    a0 += v1 * bf2f((unsigned short)(p1 & 0xFFFF)); a1 += v1 * bf2f((unsigned short)(p1 >> 16));
    a0 += v2 * bf2f((unsigned short)(p2 & 0xFFFF)); a1 += v2 * bf2f((unsigned short)(p2 >> 16));
    a0 += v3 * bf2f((unsigned short)(p3 & 0xFFFF)); a1 += v3 * bf2f((unsigned short)(p3 >> 16));
  }
  for (; e < e1; ++e) {
    int c = col[e];
    float v = adj[e];
    unsigned int p = hw2[(size_t)c * 32 + l];
    a0 += v * bf2f((unsigned short)(p & 0xFFFF));
    a1 += v * bf2f((unsigned short)(p >> 16));
  }
  float2 r; r.x = a0 + b1[2 * l]; r.y = a1 + b1[2 * l + 1];
  o2[(size_t)node * 32 + l] = r;
}

extern "C" void kernel_launch(void* const* d_in, const int* in_sizes, int n_in,
                              void* d_out, int out_size, void* d_ws, size_t ws_size,
                              hipStream_t stream) {
  const float* x   = (const float*)d_in[0];
  const float* W0  = (const float*)d_in[1];
  const float* b0  = (const float*)d_in[2];
  const float* W1  = (const float*)d_in[3];
  const float* b1  = (const float*)d_in[4];
  const float* adj = (const float*)d_in[5];
  const int* row = (const int*)d_in[6];
  const int* col = (const int*)d_in[7];
  const int N = in_sizes[0] / D_IN;
  const int E = in_sizes[5];

  char* ws = (char*)d_ws;
  int*            rp   = (int*)(ws + OFF_RP);
  unsigned short* W0t  = (unsigned short*)(ws + OFF_W0T);
  unsigned short* W1tp = (unsigned short*)(ws + OFF_W1TP);
  float*          sacc = (float*)(ws + OFF_SACC);
  float*          mean = (float*)(ws + OFF_MEAN);
  float*          istd = (float*)(ws + OFF_ISTD);
  float*          cvec = (float*)(ws + OFF_CVEC);
  unsigned short* h    = (unsigned short*)(ws + OFF_H);

  // xw (packed bf16, 100000x128 = 25.6MB) lives in d_out-as-scratch (fp32 out
  // buffer is exactly 25.6MB). hw (bf16 100000x64 = 12.8MB): in ws if it fits,
  // else overlaid on dead xw in d_out with the final fp32 out staged in the
  // dead h region and d2d-copied at the end.
  unsigned short* xw = (unsigned short*)d_out;
  const bool hw_in_ws = (ws_size >= (size_t)END_HW);
  unsigned short* hw   = hw_in_ws ? (unsigned short*)(ws + END_H) : (unsigned short*)d_out;
  float*          outd = hw_in_ws ? (float*)d_out                 : (float*)(ws + OFF_H);

  k_zero<<<1, 256, 0, stream>>>(sacc);
  k_rowptr<<<(N + 1 + 255) / 256, 256, 0, stream>>>(row, rp, N, E);
  k_transpose_w0<<<(D_IN * D_H) / 256, 256, 0, stream>>>(W0, W0t);

  k_gemm1<<<(N + 127) / 128, 256, 0, stream>>>(x, W0t, xw, N);
  k_spmm1<<<(N + 3) / 4, 256, 0, stream>>>((const unsigned int*)xw, adj, col, rp, b0,
                                           (unsigned int*)h, N);

  k_stats<<<512, 256, 0, stream>>>(h, sacc, N);
  k_redstats<<<1, 128, 0, stream>>>(sacc, mean, istd, N);
  k_prep<<<1, 256, 0, stream>>>(W1, mean, istd, W1tp, cvec);

  k_gemm2<<<(N + 127) / 128, 256, 0, stream>>>(h, W1tp, cvec, hw, N);
  k_spmm2<<<(N + 7) / 8, 256, 0, stream>>>((const unsigned int*)hw, adj, col, rp, b1,
                                           (float2*)outd, N);

  if (!hw_in_ws) {
    hipMemcpyAsync(d_out, outd, (size_t)N * D_OUT * sizeof(float),
                   hipMemcpyDeviceToDevice, stream);
  }
}

// Round 4
// 489.509 us; speedup vs baseline: 1.0538x; 1.0538x over previous
//
#include <hip/hip_runtime.h>
#include <cstdint>
#include <cstddef>

#define D_IN  512
#define D_H   128
#define D_OUT 64

typedef __attribute__((ext_vector_type(8))) short bf16x8;
typedef __attribute__((ext_vector_type(4))) float f32x4;

__device__ __forceinline__ float bf2f(unsigned short u) {
  union { unsigned int i; float f; } v; v.i = ((unsigned int)u) << 16; return v.f;
}
__device__ __forceinline__ unsigned short f2bf(float f) {
  union { unsigned int i; float f; } v; v.f = f;
  unsigned int r = v.i + 0x7FFFu + ((v.i >> 16) & 1u);
  return (unsigned short)(r >> 16);
}

// ---------------- workspace layout (bytes); ws_size ~800MB per R3 profile ----
#define OFF_RP    0u          // row_ptr int32[100001]
#define OFF_W0T   400384u     // W0^T bf16 128x512
#define OFF_W1TP  531456u     // W1'^T bf16 64x128
#define OFF_SACC  547840u     // stats accum fp32[256] (sum|sq)
#define OFF_CVEC  549888u     // fp32[64]
#define OFF_H     550912u     // h bf16-packed 100000x128
#define END_H     26150912u
#define END_HW    38950912u   // + hw bf16 100000x64

// ---- k_init: [0,RB) row_ptr binsearch | [RB,RB+TB) W0 transpose | last: zero
__global__ void k_init(const int* __restrict__ row, int* __restrict__ rp,
                       const float* __restrict__ W0, unsigned short* __restrict__ W0t,
                       float* __restrict__ sacc, int n, int e, int RB, int TB) {
  int b = blockIdx.x, t = threadIdx.x;
  if (b < RB) {
    int i = b * 256 + t;
    if (i > n) return;
    int lo = 0, hi = e;
    while (lo < hi) { int mid = (lo + hi) >> 1; if (row[mid] < i) lo = mid + 1; else hi = mid; }
    rp[i] = lo;
  } else if (b < RB + TB) {
    int idx = (b - RB) * 256 + t;          // 65536 total
    int k = idx & (D_IN - 1);
    int nn = idx >> 9;
    W0t[nn * D_IN + k] = f2bf(W0[k * D_H + nn]);
  } else {
    sacc[t] = 0.f;
  }
}

// ---- GEMM1: xw(bf16) = x(fp32) @ W0. tile 128x128, BK=32, 4 waves (2x2).
// Double-buffered LDS, ONE barrier per K-iter: prefetch tile k+1 into regs
// while MFMA consumes tile k. LDS fragment-chunk order [k8][m][8] => all
// operand reads are single ds_read_b128. fp32->bf16 conversion in staging.
__global__ __launch_bounds__(256) void k_gemm1(const float* __restrict__ A,
                                               const unsigned short* __restrict__ Bt,
                                               unsigned short* __restrict__ C,
                                               int M) {
  __shared__ unsigned short Ash[2][4 * 128 * 8];  // 2 x 8KB
  __shared__ unsigned short Bsh[2][4 * 128 * 8];  // 2 x 8KB
  const int tid  = threadIdx.x;
  const int lane = tid & 63;
  const int wave = tid >> 6;
  const int wm = (wave >> 1) * 64;
  const int wn = (wave & 1) * 64;
  const int m0 = blockIdx.x * 128;
  const int quad = lane >> 4;
  const int l16  = lane & 15;
  f32x4 acc[4][4] = {};

  // per-thread staging chunk geometry: chunk c_i = tid + i*256; m = c>>2, k8 = c&3
  int am[2], ak[2];
  const float* aptr[2];
  const unsigned short* bptr[2];
#pragma unroll
  for (int i = 0; i < 2; ++i) {
    int c = tid + i * 256;
    am[i] = c >> 2; ak[i] = c & 3;
    int gm = m0 + am[i]; if (gm >= M) gm = M - 1;
    aptr[i] = A  + (size_t)gm * D_IN + ak[i] * 8;
    bptr[i] = Bt + (size_t)am[i] * D_IN + ak[i] * 8;
  }

  f32x4 areg[2][2];
  bf16x8 breg[2];
#pragma unroll
  for (int i = 0; i < 2; ++i) {           // prefetch tile 0
    areg[i][0] = *(const f32x4*)(aptr[i]);
    areg[i][1] = *(const f32x4*)(aptr[i] + 4);
    breg[i]    = *(const bf16x8*)(bptr[i]);
  }

  const int NIT = D_IN / 32;  // 16
  for (int it = 0; it < NIT; ++it) {
    const int buf = it & 1;
    unsigned short* ash = Ash[buf];
    unsigned short* bsh = Bsh[buf];
#pragma unroll
    for (int i = 0; i < 2; ++i) {
      bf16x8 pk;
#pragma unroll
      for (int j = 0; j < 4; ++j) {
        pk[j]     = (short)f2bf(areg[i][0][j]);
        pk[4 + j] = (short)f2bf(areg[i][1][j]);
      }
      *(bf16x8*)&ash[(ak[i] * 128 + am[i]) * 8] = pk;
      *(bf16x8*)&bsh[(ak[i] * 128 + am[i]) * 8] = breg[i];
    }
    __syncthreads();
    if (it + 1 < NIT) {
      int k0 = (it + 1) * 32;
#pragma unroll
      for (int i = 0; i < 2; ++i) {
        areg[i][0] = *(const f32x4*)(aptr[i] + k0);
        areg[i][1] = *(const f32x4*)(aptr[i] + k0 + 4);
        breg[i]    = *(const bf16x8*)(bptr[i] + k0);
      }
    }
    bf16x8 af[4], bfv[4];
#pragma unroll
    for (int mf = 0; mf < 4; ++mf)
      af[mf] = *(const bf16x8*)&ash[(quad * 128 + (wm + mf * 16 + l16)) * 8];
#pragma unroll
    for (int nf = 0; nf < 4; ++nf)
      bfv[nf] = *(const bf16x8*)&bsh[(quad * 128 + (wn + nf * 16 + l16)) * 8];
#pragma unroll
    for (int mf = 0; mf < 4; ++mf)
#pragma unroll
      for (int nf = 0; nf < 4; ++nf)
        acc[mf][nf] = __builtin_amdgcn_mfma_f32_16x16x32_bf16(af[mf], bfv[nf], acc[mf][nf], 0, 0, 0);
    // single barrier/iter is safe: a wave writing buf^1 at it+1 has passed
    // barrier(it), which required all waves to finish compute(it-1) on buf^1.
  }
  // C/D layout: row = quad*4 + i, col = lane&15  [m89/m91-verified]
#pragma unroll
  for (int mf = 0; mf < 4; ++mf)
#pragma unroll
    for (int nf = 0; nf < 4; ++nf)
#pragma unroll
      for (int i = 0; i < 4; ++i) {
        int r = m0 + wm + mf * 16 + quad * 4 + i;
        int cc = wn + nf * 16 + l16;
        if (r < M) C[(size_t)r * D_H + cc] = f2bf(acc[mf][nf][i]);
      }
}

// ---- SpMM1: h = relu(adj @ xw + b0); one wave/node, lane = packed feat pair.
// Masked unroll-8: tail edges use clamped index + zero weight (wave-uniform
// mask) so 8 gathers are always in flight — no serial remainder chain.
__global__ __launch_bounds__(256) void k_spmm1(const unsigned int* __restrict__ xw2,
                                               const float* __restrict__ adj,
                                               const int* __restrict__ col,
                                               const int* __restrict__ rp,
                                               const float* __restrict__ b0,
                                               unsigned int* __restrict__ h2,
                                               int n) {
  int node = blockIdx.x * 4 + (threadIdx.x >> 6);
  if (node >= n) return;
  int l = threadIdx.x & 63;
  int e0 = rp[node], e1 = rp[node + 1];
  float a0 = 0.f, a1 = 0.f;
  for (int e = e0; e < e1; e += 8) {
    int   idx[8]; float w[8];
#pragma unroll
    for (int j = 0; j < 8; ++j) {
      int ee = e + j;
      int ec = ee < e1 ? ee : e0;
      idx[j] = col[ec];
      w[j] = ee < e1 ? adj[ec] : 0.f;
    }
#pragma unroll
    for (int j = 0; j < 8; ++j) {
      unsigned int p = xw2[(size_t)idx[j] * 64 + l];
      a0 += w[j] * bf2f((unsigned short)(p & 0xFFFF));
      a1 += w[j] * bf2f((unsigned short)(p >> 16));
    }
  }
  float r0 = fmaxf(a0 + b0[2 * l], 0.f);
  float r1 = fmaxf(a1 + b0[2 * l + 1], 0.f);
  h2[(size_t)node * 64 + l] = ((unsigned int)f2bf(r1) << 16) | (unsigned int)f2bf(r0);
}

// ---- BN stats: packed 4B reads; block-level LDS reduce, then 256 atomics ----
__global__ __launch_bounds__(256) void k_stats(const unsigned int* __restrict__ h2,
                                               float* __restrict__ sacc, int n) {
  __shared__ float sA[256], sB[256], qA[256], qB[256];
  int t = threadIdx.x;
  int f2 = t & 63, rg = t >> 6;
  float s0 = 0.f, s1 = 0.f, q0 = 0.f, q1 = 0.f;
  for (int r = blockIdx.x * 4 + rg; r < n; r += gridDim.x * 4) {
    unsigned int p = h2[(size_t)r * 64 + f2];
    float v0 = bf2f((unsigned short)(p & 0xFFFF));
    float v1 = bf2f((unsigned short)(p >> 16));
    s0 += v0; s1 += v1; q0 += v0 * v0; q1 += v1 * v1;
  }
  sA[t] = s0; sB[t] = s1; qA[t] = q0; qB[t] = q1;
  __syncthreads();
  if (t < 64) {
    float S0 = sA[t] + sA[t + 64] + sA[t + 128] + sA[t + 192];
    float S1 = sB[t] + sB[t + 64] + sB[t + 128] + sB[t + 192];
    float Q0 = qA[t] + qA[t + 64] + qA[t + 128] + qA[t + 192];
    float Q1 = qB[t] + qB[t + 64] + qB[t + 128] + qB[t + 192];
    atomicAdd(&sacc[2 * t],           S0);
    atomicAdd(&sacc[2 * t + 1],       S1);
    atomicAdd(&sacc[128 + 2 * t],     Q0);
    atomicAdd(&sacc[128 + 2 * t + 1], Q1);
  }
}

// ---- prep2: mean/istd from sacc (LDS-only) + fold BN into W1', cvec ---------
__global__ void k_prep2(const float* __restrict__ sacc, const float* __restrict__ W1,
                        unsigned short* __restrict__ W1tp, float* __restrict__ cvec,
                        int n) {
  __shared__ float mean_s[128], istd_s[128];
  int t = threadIdx.x;  // 256
  if (t < 128) {
    float m = sacc[t] / (float)n;
    float var = sacc[128 + t] / (float)n - m * m;
    if (var < 0.f) var = 0.f;
    mean_s[t] = m;
    istd_s[t] = rsqrtf(var + 1e-5f);
  }
  __syncthreads();
  for (int idx = t; idx < D_OUT * D_H; idx += 256) {
    int nn = idx >> 7, k = idx & 127;
    W1tp[nn * D_H + k] = f2bf(istd_s[k] * W1[k * D_OUT + nn]);
  }
  if (t < D_OUT) {
    float a = 0.f;
    for (int k = 0; k < D_H; ++k) a += mean_s[k] * istd_s[k] * W1[k * D_OUT + t];
    cvec[t] = -a;
  }
}

// ---- GEMM2: hw(bf16) = h(bf16) @ W1' + c. tile 128x64, BK=32, 4 waves -------
__global__ __launch_bounds__(256) void k_gemm2(const unsigned short* __restrict__ A,
                                               const unsigned short* __restrict__ Bt,
                                               const float* __restrict__ cvec,
                                               unsigned short* __restrict__ Cout,
                                               int M) {
  __shared__ unsigned short Ash[4 * 128 * 8];
  __shared__ unsigned short Bsh[4 * 64 * 8];
  const int tid  = threadIdx.x;
  const int lane = tid & 63;
  const int wave = tid >> 6;
  const int wm = wave * 32;
  const int m0 = blockIdx.x * 128;
  const int quad = lane >> 4;
  const int l16  = lane & 15;
  f32x4 acc[2][4] = {};

  for (int k0 = 0; k0 < D_H; k0 += 32) {
    __syncthreads();
#pragma unroll
    for (int i = 0; i < 2; ++i) {
      int c = tid + i * 256;
      int m = c >> 2, k8 = c & 3;
      int gm = m0 + m; if (gm >= M) gm = M - 1;
      *(bf16x8*)&Ash[(k8 * 128 + m) * 8] =
          *(const bf16x8*)&A[(size_t)gm * D_H + k0 + k8 * 8];
    }
    {
      int nn = tid >> 2, k8 = tid & 3;
      *(bf16x8*)&Bsh[(k8 * 64 + nn) * 8] =
          *(const bf16x8*)&Bt[(size_t)nn * D_H + k0 + k8 * 8];
    }
    __syncthreads();
    bf16x8 af[2], bfv[4];
#pragma unroll
    for (int mf = 0; mf < 2; ++mf)
      af[mf] = *(const bf16x8*)&Ash[(quad * 128 + (wm + mf * 16 + l16)) * 8];
#pragma unroll
    for (int nf = 0; nf < 4; ++nf)
      bfv[nf] = *(const bf16x8*)&Bsh[(quad * 64 + (nf * 16 + l16)) * 8];
#pragma unroll
    for (int mf = 0; mf < 2; ++mf)
#pragma unroll
      for (int nf = 0; nf < 4; ++nf)
        acc[mf][nf] = __builtin_amdgcn_mfma_f32_16x16x32_bf16(af[mf], bfv[nf], acc[mf][nf], 0, 0, 0);
  }
#pragma unroll
  for (int mf = 0; mf < 2; ++mf)
#pragma unroll
    for (int nf = 0; nf < 4; ++nf)
#pragma unroll
      for (int i = 0; i < 4; ++i) {
        int r = m0 + wm + mf * 16 + quad * 4 + i;
        int cc = nf * 16 + l16;
        if (r < M) Cout[(size_t)r * 64 + cc] = f2bf(acc[mf][nf][i] + cvec[cc]);
      }
}

// ---- SpMM2: out(fp32) = adj @ hw + b1; half-wave/node, masked unroll-8 ------
__global__ __launch_bounds__(256) void k_spmm2(const unsigned int* __restrict__ hw2,
                                               const float* __restrict__ adj,
                                               const int* __restrict__ col,
                                               const int* __restrict__ rp,
                                               const float* __restrict__ b1,
                                               float2* __restrict__ o2,
                                               int n) {
  int node = blockIdx.x * 8 + (threadIdx.x >> 5);
  if (node >= n) return;
  int l = threadIdx.x & 31;
  int e0 = rp[node], e1 = rp[node + 1];
  float a0 = 0.f, a1 = 0.f;
  for (int e = e0; e < e1; e += 8) {
    int   idx[8]; float w[8];
#pragma unroll
    for (int j = 0; j < 8; ++j) {
      int ee = e + j;
      int ec = ee < e1 ? ee : e0;
      idx[j] = col[ec];
      w[j] = ee < e1 ? adj[ec] : 0.f;
    }
#pragma unroll
    for (int j = 0; j < 8; ++j) {
      unsigned int p = hw2[(size_t)idx[j] * 32 + l];
      a0 += w[j] * bf2f((unsigned short)(p & 0xFFFF));
      a1 += w[j] * bf2f((unsigned short)(p >> 16));
    }
  }
  float2 r; r.x = a0 + b1[2 * l]; r.y = a1 + b1[2 * l + 1];
  o2[(size_t)node * 32 + l] = r;
}

extern "C" void kernel_launch(void* const* d_in, const int* in_sizes, int n_in,
                              void* d_out, int out_size, void* d_ws, size_t ws_size,
                              hipStream_t stream) {
  const float* x   = (const float*)d_in[0];
  const float* W0  = (const float*)d_in[1];
  const float* b0  = (const float*)d_in[2];
  const float* W1  = (const float*)d_in[3];
  const float* b1  = (const float*)d_in[4];
  const float* adj = (const float*)d_in[5];
  const int* row = (const int*)d_in[6];
  const int* col = (const int*)d_in[7];
  const int N = in_sizes[0] / D_IN;
  const int E = in_sizes[5];

  char* ws = (char*)d_ws;
  int*            rp   = (int*)(ws + OFF_RP);
  unsigned short* W0t  = (unsigned short*)(ws + OFF_W0T);
  unsigned short* W1tp = (unsigned short*)(ws + OFF_W1TP);
  float*          sacc = (float*)(ws + OFF_SACC);
  float*          cvec = (float*)(ws + OFF_CVEC);
  unsigned short* h    = (unsigned short*)(ws + OFF_H);

  // xw (packed bf16 100000x128 = 25.6MB) overlays d_out (fp32 out = 25.6MB).
  // hw in ws (R3 profile: ws_size ~800MB); keep the fallback branch anyway.
  unsigned short* xw = (unsigned short*)d_out;
  const bool hw_in_ws = (ws_size >= (size_t)END_HW);
  unsigned short* hw   = hw_in_ws ? (unsigned short*)(ws + END_H) : (unsigned short*)d_out;
  float*          outd = hw_in_ws ? (float*)d_out                 : (float*)(ws + OFF_H);

  const int RB = (N + 1 + 255) / 256;       // rowptr blocks
  const int TB = (D_IN * D_H) / 256;        // transpose blocks
  k_init<<<RB + TB + 1, 256, 0, stream>>>(row, rp, W0, W0t, sacc, N, E, RB, TB);

  k_gemm1<<<(N + 127) / 128, 256, 0, stream>>>(x, W0t, xw, N);
  k_spmm1<<<(N + 3) / 4, 256, 0, stream>>>((const unsigned int*)xw, adj, col, rp, b0,
                                           (unsigned int*)h, N);
  k_stats<<<512, 256, 0, stream>>>((const unsigned int*)h, sacc, N);
  k_prep2<<<1, 256, 0, stream>>>(sacc, W1, W1tp, cvec, N);
  k_gemm2<<<(N + 127) / 128, 256, 0, stream>>>(h, W1tp, cvec, hw, N);
  k_spmm2<<<(N + 7) / 8, 256, 0, stream>>>((const unsigned int*)hw, adj, col, rp, b1,
                                           (float2*)outd, N);

  if (!hw_in_ws) {
    hipMemcpyAsync(d_out, outd, (size_t)N * D_OUT * sizeof(float),
                   hipMemcpyDeviceToDevice, stream);
  }
}